// Round 1
// baseline (853.884 us; speedup 1.0000x reference)
//
#include <hip/hip_runtime.h>
#include <stdint.h>

#define D_IN 250
#define H_DIM 100
#define GP 112            // padded gate width (7 x 16)
#define NT1 42            // stage1 n-tiles: 6 gates x 7
#define NT2 21            // 3 gates x 7
#define KS1 8             // K=256 (250 padded) / 32
#define KS2 4             // K=128 (100 padded) / 32
#define BM 128            // rows per block
#define NTHREADS 512

#define P1_CHUNK_B (NT1*64*8*2)   // 43008 bytes per K-chunk
#define P2_CHUNK_B (NT2*64*8*2)   // 21504
#define P1_ELEMS (KS1*NT1*64*8)   // 172032
#define P2_ELEMS (KS2*NT2*64*8)   // 43008
#define P2_OFF_B  (P1_CHUNK_B*KS1)            // 344064
#define P4A_OFF_B (P2_OFF_B + P2_CHUNK_B*KS2) // 430080
#define P4B_OFF_B (P4A_OFF_B + P2_CHUNK_B*KS2)// 516096

typedef __bf16 bf16x8 __attribute__((ext_vector_type(8)));
typedef float f32x4 __attribute__((ext_vector_type(4)));

static __device__ __forceinline__ uint16_t f2bf(float f) {
  uint32_t u = __builtin_bit_cast(uint32_t, f);
  u = (u + 0x7FFFu + ((u >> 16) & 1u)) >> 16;
  return (uint16_t)u;
}
static __device__ __forceinline__ float bf2f(uint16_t h) {
  uint32_t u = ((uint32_t)h) << 16;
  return __builtin_bit_cast(float, u);
}
static __device__ __forceinline__ float sigmoidf_(float x) {
  return 1.0f / (1.0f + __expf(-x));
}
static __device__ __forceinline__ float tanhf_(float x) {
  return 2.0f / (1.0f + __expf(-2.0f * x)) - 1.0f;
}
static __device__ __forceinline__ float xpget(uint2 p, int r) {
  uint32_t w = (r & 2) ? p.y : p.x;
  uint16_t u = (r & 1) ? (uint16_t)(w >> 16) : (uint16_t)(w & 0xFFFFu);
  return bf2f(u);
}

// ---------------- weight prepack: fp32 -> bf16 B-fragment layout -------------
// P1[ks][nt][lane][j]  : B1[k][n], k=ks*32+(lane>>4)*8+j, npad=nt*16+(lane&15)
// gates stage1: [Wi_r, Wi_z, Wi_n, W_z, W_r, W_hn], each padded to 112 cols
__global__ void prepack_kernel(const float* __restrict__ Wi, const float* __restrict__ Wh,
                               const float* __restrict__ W_z, const float* __restrict__ U_z,
                               const float* __restrict__ Us_z, const float* __restrict__ W_r,
                               const float* __restrict__ U_r, const float* __restrict__ Us_r,
                               const float* __restrict__ W_hn, const float* __restrict__ U_hn,
                               const float* __restrict__ Us_hn, uint16_t* __restrict__ ws) {
  int idx = blockIdx.x * blockDim.x + threadIdx.x;
  if (idx < P1_ELEMS) {
    int j = idx & 7, lane = (idx >> 3) & 63;
    int v = idx >> 9;              // ks*NT1 + nt
    int nt = v % NT1, ks = v / NT1;
    int k = ks * 32 + ((lane >> 4) << 3) + j;
    int npad = nt * 16 + (lane & 15);
    int g = npad / GP, c = npad % GP;
    float val = 0.f;
    if (k < D_IN && c < H_DIM) {
      const float* row;
      if (g < 3)        row = Wi   + (size_t)(g * H_DIM + c) * D_IN;
      else if (g == 3)  row = W_z  + (size_t)c * D_IN;
      else if (g == 4)  row = W_r  + (size_t)c * D_IN;
      else              row = W_hn + (size_t)c * D_IN;
      val = row[k];
    }
    ws[idx] = f2bf(val);
    return;
  }
  idx -= P1_ELEMS;
  int sec = idx / P2_ELEMS;        // 0=Wh, 1=U(z,r,hn), 2=Us(z,r,hn)
  if (sec >= 3) return;
  int id2 = idx % P2_ELEMS;
  int j = id2 & 7, lane = (id2 >> 3) & 63;
  int v = id2 >> 9;                // ks*NT2 + nt
  int nt = v % NT2, ks = v / NT2;
  int k = ks * 32 + ((lane >> 4) << 3) + j;
  int npad = nt * 16 + (lane & 15);
  int g = npad / GP, c = npad % GP;
  float val = 0.f;
  if (k < H_DIM && c < H_DIM) {
    const float* row;
    if (sec == 0)      row = Wh + (size_t)(g * H_DIM + c) * H_DIM;
    else if (sec == 1) row = (g == 0 ? U_z  : g == 1 ? U_r  : U_hn)  + (size_t)c * H_DIM;
    else               row = (g == 0 ? Us_z : g == 1 ? Us_r : Us_hn) + (size_t)c * H_DIM;
    val = row[k];
  }
  ws[P1_ELEMS + sec * P2_ELEMS + id2] = f2bf(val);
}

// ---------------------------- fused GRU kernel -------------------------------
__global__ __launch_bounds__(NTHREADS, 2) void gru_fused(
    const float* __restrict__ x, const float* __restrict__ hp_g,
    const float* __restrict__ hs_g, const float* __restrict__ bi,
    const float* __restrict__ bh, const uint16_t* __restrict__ ws,
    float* __restrict__ out) {
  __shared__ uint16_t ldsX[BM * 256];   // 65536 B; after stage1: Hp [0..16384) + HsNew [16384..32768)
  __shared__ uint16_t ldsHs[BM * 128];  // 32768 B
  __shared__ uint16_t ldsB[NT1 * 64 * 8]; // 43008 B weight-chunk staging

  const int tid = threadIdx.x;
  const int lane = tid & 63, wid = tid >> 6;
  const int q = lane >> 4, cl = lane & 15;
  const int rowbase = blockIdx.x * BM;

  // ---- phase 0: stage X (bf16, swizzled) and Hs into LDS ----
  #pragma unroll
  for (int pass = 0; pass < 32; ++pass) {           // X: 4 rows/pass, float2 (row stride 1000B -> 8B aligned)
    int row = pass * 4 + (tid >> 7);
    int c2 = (tid & 127) * 2;
    float v0 = 0.f, v1 = 0.f;
    if (c2 < D_IN) { float2 f = *(const float2*)(x + (size_t)(rowbase + row) * D_IN + c2); v0 = f.x; v1 = f.y; }
    ushort2 b; b.x = f2bf(v0); b.y = f2bf(v1);
    int byteoff = row * 512 + ((c2 * 2) ^ ((row & 7) << 4));
    *(ushort2*)((char*)ldsX + byteoff) = b;
  }
  #pragma unroll
  for (int pass = 0; pass < 8; ++pass) {            // Hs: 16 rows/pass, float4 (row stride 400B -> 16B aligned)
    int row = pass * 16 + (tid >> 5);
    int c4 = (tid & 31) * 4;
    float v0 = 0.f, v1 = 0.f, v2 = 0.f, v3 = 0.f;
    if (c4 < H_DIM) { float4 f = *(const float4*)(hs_g + (size_t)(rowbase + row) * H_DIM + c4); v0 = f.x; v1 = f.y; v2 = f.z; v3 = f.w; }
    ushort4 b; b.x = f2bf(v0); b.y = f2bf(v1); b.z = f2bf(v2); b.w = f2bf(v3);
    int byteoff = row * 256 + ((c4 * 2) ^ ((row & 7) << 4));
    *(ushort4*)((char*)ldsHs + byteoff) = b;
  }

  // ---- stage1: [BM,672] = X @ Wx^T  (K=256) ----
  f32x4 acc1[NT1];
  #pragma unroll
  for (int i = 0; i < NT1; ++i) acc1[i] = (f32x4)(0.f);
  const int arow = wid * 16 + cl;
  for (int ks = 0; ks < KS1; ++ks) {
    __syncthreads();
    {
      const uint4* src = (const uint4*)((const char*)ws + (size_t)ks * P1_CHUNK_B);
      uint4* dst = (uint4*)ldsB;
      for (int i = tid; i < P1_CHUNK_B / 16; i += NTHREADS) dst[i] = src[i];
    }
    __syncthreads();
    int abyte = arow * 512 + (((ks * 64) + q * 16) ^ ((arow & 7) << 4));
    bf16x8 a = *(const bf16x8*)((const char*)ldsX + abyte);
    #pragma unroll
    for (int nt = 0; nt < NT1; ++nt) {
      bf16x8 b = *(const bf16x8*)((const char*)ldsB + nt * 1024 + lane * 16);
      acc1[nt] = __builtin_amdgcn_mfma_f32_16x16x32_bf16(a, b, acc1[nt], 0, 0, 0);
    }
  }

  // convert all stage1 accs to packed bf16 (register pressure)
  uint2 xp1[NT1];
  #pragma unroll
  for (int i = 0; i < NT1; ++i) {
    f32x4 v = acc1[i];
    xp1[i].x = (uint32_t)f2bf(v[0]) | ((uint32_t)f2bf(v[1]) << 16);
    xp1[i].y = (uint32_t)f2bf(v[2]) | ((uint32_t)f2bf(v[3]) << 16);
  }

  // ---- stage2: gh [BM,336] = Hs @ Wh^T (K=128) ----
  f32x4 acc2[NT2];
  #pragma unroll
  for (int i = 0; i < NT2; ++i) acc2[i] = (f32x4)(0.f);
  for (int ks = 0; ks < KS2; ++ks) {
    __syncthreads();
    {
      const uint4* src = (const uint4*)((const char*)ws + P2_OFF_B + (size_t)ks * P2_CHUNK_B);
      uint4* dst = (uint4*)ldsB;
      for (int i = tid; i < P2_CHUNK_B / 16; i += NTHREADS) dst[i] = src[i];
    }
    __syncthreads();
    int abyte = arow * 256 + (((ks * 64) + q * 16) ^ ((arow & 7) << 4));
    bf16x8 a = *(const bf16x8*)((const char*)ldsHs + abyte);
    #pragma unroll
    for (int nt = 0; nt < NT2; ++nt) {
      bf16x8 b = *(const bf16x8*)((const char*)ldsB + nt * 1024 + lane * 16);
      acc2[nt] = __builtin_amdgcn_mfma_f32_16x16x32_bf16(a, b, acc2[nt], 0, 0, 0);
    }
  }

  // ---- stage Hp into LDS (alias of ldsX lower half), stage3 elementwise -> HsNew ----
  uint16_t* ldsHp  = ldsX;
  uint16_t* ldsHsN = ldsX + BM * 128;
  __syncthreads();   // everyone done with ldsX (stage1) before overwrite
  #pragma unroll
  for (int pass = 0; pass < 8; ++pass) {
    int row = pass * 16 + (tid >> 5);
    int c4 = (tid & 31) * 4;
    float v0 = 0.f, v1 = 0.f, v2 = 0.f, v3 = 0.f;
    if (c4 < H_DIM) { float4 f = *(const float4*)(hp_g + (size_t)(rowbase + row) * H_DIM + c4); v0 = f.x; v1 = f.y; v2 = f.z; v3 = f.w; }
    ushort4 b; b.x = f2bf(v0); b.y = f2bf(v1); b.z = f2bf(v2); b.w = f2bf(v3);
    int byteoff = row * 256 + ((c4 * 2) ^ ((row & 7) << 4));
    *(ushort4*)((char*)ldsHp + byteoff) = b;
  }
  // stage3: shared-GRU cell elementwise (all register-local thanks to 112 padding)
  #pragma unroll
  for (int t = 0; t < 7; ++t) {
    int c = t * 16 + cl;
    bool valid = c < H_DIM;
    float bir = 0, biz = 0, bin = 0, bhr = 0, bhz = 0, bhn = 0;
    if (valid) {
      bir = bi[c]; biz = bi[H_DIM + c]; bin = bi[2 * H_DIM + c];
      bhr = bh[c]; bhz = bh[H_DIM + c]; bhn = bh[2 * H_DIM + c];
    }
    #pragma unroll
    for (int r = 0; r < 4; ++r) {
      int rl = wid * 16 + q * 4 + r;
      float gir = xpget(xp1[t], r)      + bir;
      float giz = xpget(xp1[7 + t], r)  + biz;
      float gin = xpget(xp1[14 + t], r) + bin;
      float ghr = acc2[t][r]      + bhr;
      float ghz = acc2[7 + t][r]  + bhz;
      float ghn = acc2[14 + t][r] + bhn;
      float rr = sigmoidf_(gir + ghr);
      float zz = sigmoidf_(giz + ghz);
      float nn = tanhf_(gin + rr * ghn);
      int hb = rl * 256 + ((c * 2) ^ ((rl & 7) << 4));
      float hsp = bf2f(*(const uint16_t*)((const char*)ldsHs + hb));
      float hsn = (1.f - zz) * nn + zz * hsp;
      *(uint16_t*)((char*)ldsHsN + hb) = f2bf(hsn);
    }
  }
  #pragma unroll
  for (int r = 0; r < 4; ++r) {   // zero pad cols [112,128) of HsNew
    int rl = wid * 16 + q * 4 + r;
    int c = GP + cl;
    int hb = rl * 256 + ((c * 2) ^ ((rl & 7) << 4));
    *(uint16_t*)((char*)ldsHsN + hb) = 0;
  }

  // ---- stage4: U-proj (from Hp) and Us-proj (from HsNew), K=128 each ----
  f32x4 acc4a[NT2], acc4b[NT2];
  #pragma unroll
  for (int i = 0; i < NT2; ++i) { acc4a[i] = (f32x4)(0.f); acc4b[i] = (f32x4)(0.f); }
  for (int ks = 0; ks < KS2; ++ks) {
    __syncthreads();
    {
      const uint4* srcA = (const uint4*)((const char*)ws + P4A_OFF_B + (size_t)ks * P2_CHUNK_B);
      const uint4* srcB = (const uint4*)((const char*)ws + P4B_OFF_B + (size_t)ks * P2_CHUNK_B);
      uint4* dst = (uint4*)ldsB;
      for (int i = tid; i < P2_CHUNK_B / 16; i += NTHREADS) dst[i] = srcA[i];
      for (int i = tid; i < P2_CHUNK_B / 16; i += NTHREADS) dst[P2_CHUNK_B / 16 + i] = srcB[i];
    }
    __syncthreads();
    int abyte = arow * 256 + (((ks * 64) + q * 16) ^ ((arow & 7) << 4));
    bf16x8 ahp  = *(const bf16x8*)((const char*)ldsHp  + abyte);
    bf16x8 ahsn = *(const bf16x8*)((const char*)ldsHsN + abyte);
    #pragma unroll
    for (int nt = 0; nt < NT2; ++nt) {
      bf16x8 ba = *(const bf16x8*)((const char*)ldsB + nt * 1024 + lane * 16);
      bf16x8 bb = *(const bf16x8*)((const char*)ldsB + P2_CHUNK_B + nt * 1024 + lane * 16);
      acc4a[nt] = __builtin_amdgcn_mfma_f32_16x16x32_bf16(ahp,  ba, acc4a[nt], 0, 0, 0);
      acc4b[nt] = __builtin_amdgcn_mfma_f32_16x16x32_bf16(ahsn, bb, acc4b[nt], 0, 0, 0);
    }
  }

  // ---- stage5: task-specific elementwise + store ----
  #pragma unroll
  for (int t = 0; t < 7; ++t) {
    int c = t * 16 + cl;
    bool valid = c < H_DIM;
    #pragma unroll
    for (int r = 0; r < 4; ++r) {
      int rl = wid * 16 + q * 4 + r;
      float xz = xpget(xp1[21 + t], r);
      float xr = xpget(xp1[28 + t], r);
      float xh = xpget(xp1[35 + t], r);
      float z2 = sigmoidf_(xz + acc4a[t][r]      + acc4b[t][r]);
      float r2 = sigmoidf_(xr + acc4a[7 + t][r]  + acc4b[7 + t][r]);
      float nm = tanhf_(xh + r2 * acc4a[14 + t][r] + acc4b[14 + t][r]);
      int hb = rl * 256 + ((c * 2) ^ ((rl & 7) << 4));
      float hpv = bf2f(*(const uint16_t*)((const char*)ldsHp + hb));
      float hnew = (1.f - z2) * nm + z2 * hpv;
      if (valid) out[(size_t)(rowbase + rl) * H_DIM + c] = hnew;
    }
  }
}

extern "C" void kernel_launch(void* const* d_in, const int* in_sizes, int n_in,
                              void* d_out, int out_size, void* d_ws, size_t ws_size,
                              hipStream_t stream) {
  const float* x    = (const float*)d_in[0];
  const float* h_p  = (const float*)d_in[1];
  const float* h_s  = (const float*)d_in[2];
  const float* Wi   = (const float*)d_in[3];
  const float* Wh   = (const float*)d_in[4];
  const float* bi   = (const float*)d_in[5];
  const float* bh   = (const float*)d_in[6];
  const float* W_z  = (const float*)d_in[7];
  const float* U_z  = (const float*)d_in[8];
  const float* Us_z = (const float*)d_in[9];
  const float* W_r  = (const float*)d_in[10];
  const float* U_r  = (const float*)d_in[11];
  const float* Us_r = (const float*)d_in[12];
  const float* W_hn = (const float*)d_in[13];
  const float* U_hn = (const float*)d_in[14];
  const float* Us_hn= (const float*)d_in[15];
  uint16_t* ws = (uint16_t*)d_ws;
  float* out = (float*)d_out;

  int rows = in_sizes[0] / D_IN;          // 262144
  int total = P1_ELEMS + 3 * P2_ELEMS;    // 301056
  prepack_kernel<<<(total + 255) / 256, 256, 0, stream>>>(
      Wi, Wh, W_z, U_z, Us_z, W_r, U_r, Us_r, W_hn, U_hn, Us_hn, ws);
  gru_fused<<<rows / BM, NTHREADS, 0, stream>>>(x, h_p, h_s, bi, bh, ws, out);
}

// Round 2
// 735.884 us; speedup vs baseline: 1.1604x; 1.1604x over previous
//
#include <hip/hip_runtime.h>
#include <stdint.h>

#define D_IN 250
#define H_DIM 100
#define GP 112            // padded gate width (7 x 16)
#define KS1 8             // K=256 (250 padded) / 32
#define KS2 4             // K=128 (100 padded) / 32
#define BM 128            // rows per block
#define NTHREADS 512

#define CHUNK_E (21*512)          // 10752 elems (21504 B) per K-chunk of a 21-tile section
#define CHUNK_B (CHUNK_E*2)
// prepacked ws element offsets
#define S1A_OFF 0                 // gi  = Wi (r,z,n), K=256, 8 chunks
#define S1B_OFF (KS1*CHUNK_E)     // 86016: task W (z,r,hn), K=256, 8 chunks
#define S2_OFF  (2*KS1*CHUNK_E)   // 172032: Wh (r,z,n), K=128, 4 chunks
#define S4A_OFF (S2_OFF+KS2*CHUNK_E)  // 215040: U (z,r,hn)
#define S4B_OFF (S4A_OFF+KS2*CHUNK_E) // 258048: Us (z,r,hn)
#define TOTAL_E (S4B_OFF+KS2*CHUNK_E) // 301056

typedef __bf16 bf16x8 __attribute__((ext_vector_type(8)));
typedef float f32x4 __attribute__((ext_vector_type(4)));

static __device__ __forceinline__ uint16_t f2bf(float f) {
  uint32_t u = __builtin_bit_cast(uint32_t, f);
  u = (u + 0x7FFFu + ((u >> 16) & 1u)) >> 16;
  return (uint16_t)u;
}
static __device__ __forceinline__ float bf2f(uint16_t h) {
  uint32_t u = ((uint32_t)h) << 16;
  return __builtin_bit_cast(float, u);
}
static __device__ __forceinline__ float sigmoidf_(float x) {
  return 1.0f / (1.0f + __expf(-x));
}
static __device__ __forceinline__ float tanhf_(float x) {
  return 2.0f / (1.0f + __expf(-2.0f * x)) - 1.0f;
}
static __device__ __forceinline__ float xpget(uint2 p, int r) {
  uint32_t w = (r & 2) ? p.y : p.x;
  uint16_t u = (r & 1) ? (uint16_t)(w >> 16) : (uint16_t)(w & 0xFFFFu);
  return bf2f(u);
}

// ---------------- weight prepack: fp32 -> bf16 B-fragment layout -------------
// layout per chunk: [nt(21)][lane(64)][j(8)] ; k = ks*32+(lane>>4)*8+j, npad = nt*16+(lane&15)
__global__ void prepack_kernel(const float* __restrict__ Wi, const float* __restrict__ Wh,
                               const float* __restrict__ W_z, const float* __restrict__ U_z,
                               const float* __restrict__ Us_z, const float* __restrict__ W_r,
                               const float* __restrict__ U_r, const float* __restrict__ Us_r,
                               const float* __restrict__ W_hn, const float* __restrict__ U_hn,
                               const float* __restrict__ Us_hn, uint16_t* __restrict__ ws) {
  int idx = blockIdx.x * blockDim.x + threadIdx.x;
  if (idx >= TOTAL_E) return;
  float val = 0.f;
  if (idx < 2 * KS1 * CHUNK_E) {
    int sec = idx / (KS1 * CHUNK_E);       // 0: gi (Wi),  1: task W
    int a = idx % (KS1 * CHUNK_E);
    int j = a & 7, lane = (a >> 3) & 63;
    int v = a >> 9;                        // ks*21 + nt
    int nt = v % 21, ks = v / 21;
    int k = ks * 32 + ((lane >> 4) << 3) + j;
    int npad = nt * 16 + (lane & 15);
    int g = npad / GP, c = npad % GP;
    if (k < D_IN && c < H_DIM) {
      const float* row;
      if (sec == 0) row = Wi + (size_t)(g * H_DIM + c) * D_IN;
      else          row = (g == 0 ? W_z : g == 1 ? W_r : W_hn) + (size_t)c * D_IN;
      val = row[k];
    }
  } else {
    int b = idx - 2 * KS1 * CHUNK_E;
    int sec = b / (KS2 * CHUNK_E);         // 0: Wh, 1: U, 2: Us
    int a = b % (KS2 * CHUNK_E);
    int j = a & 7, lane = (a >> 3) & 63;
    int v = a >> 9;
    int nt = v % 21, ks = v / 21;
    int k = ks * 32 + ((lane >> 4) << 3) + j;
    int npad = nt * 16 + (lane & 15);
    int g = npad / GP, c = npad % GP;
    if (k < H_DIM && c < H_DIM) {
      const float* row;
      if (sec == 0)      row = Wh + (size_t)(g * H_DIM + c) * H_DIM;
      else if (sec == 1) row = (g == 0 ? U_z  : g == 1 ? U_r  : U_hn)  + (size_t)c * H_DIM;
      else               row = (g == 0 ? Us_z : g == 1 ? Us_r : Us_hn) + (size_t)c * H_DIM;
      val = row[k];
    }
  }
  ws[idx] = f2bf(val);
}

// --------------------------- fused kernel helpers ----------------------------
static __device__ __forceinline__ void stageB(const uint16_t* __restrict__ ws, int elemoff,
                                              uint16_t* __restrict__ ldsB, int tid) {
  const uint4* src = (const uint4*)(ws + elemoff);
  uint4* dst = (uint4*)ldsB;
  #pragma unroll
  for (int i = 0; i < 3; ++i) {
    int idx = tid + i * NTHREADS;
    if (idx < CHUNK_B / 16) dst[idx] = src[idx];
  }
}

template <int NKS, int AROWB>
static __device__ __forceinline__ void gemm21(const uint16_t* __restrict__ ws, int sec_off,
                                              const uint16_t* __restrict__ ldsA,
                                              uint16_t* __restrict__ ldsB,
                                              f32x4* __restrict__ acc,
                                              int tid, int lane, int arow, int q) {
  #pragma unroll
  for (int i = 0; i < 21; ++i) acc[i] = (f32x4)(0.f);
  for (int ks = 0; ks < NKS; ++ks) {
    __syncthreads();
    stageB(ws, sec_off + ks * CHUNK_E, ldsB, tid);
    __syncthreads();
    int abyte = arow * AROWB + (((ks * 64) + q * 16) ^ ((arow & 7) << 4));
    bf16x8 a = *(const bf16x8*)((const char*)ldsA + abyte);
    #pragma unroll
    for (int nt = 0; nt < 21; ++nt) {
      bf16x8 b = *(const bf16x8*)((const char*)ldsB + nt * 1024 + lane * 16);
      acc[nt] = __builtin_amdgcn_mfma_f32_16x16x32_bf16(a, b, acc[nt], 0, 0, 0);
    }
  }
}

static __device__ __forceinline__ void pack21(const f32x4* __restrict__ acc, uint2* __restrict__ p) {
  #pragma unroll
  for (int i = 0; i < 21; ++i) {
    f32x4 v = acc[i];
    p[i].x = (uint32_t)f2bf(v[0]) | ((uint32_t)f2bf(v[1]) << 16);
    p[i].y = (uint32_t)f2bf(v[2]) | ((uint32_t)f2bf(v[3]) << 16);
  }
}

// ---------------------------- fused GRU kernel -------------------------------
__global__ __launch_bounds__(NTHREADS, 2) void gru_fused(
    const float* __restrict__ x, const float* __restrict__ hp_g,
    const float* __restrict__ hs_g, const float* __restrict__ bi,
    const float* __restrict__ bh, const uint16_t* __restrict__ ws,
    float* __restrict__ out) {
  __shared__ __align__(16) uint16_t ldsX[BM * 256];   // 65536 B (X, bf16, swizzled)
  __shared__ __align__(16) uint16_t ldsHs[BM * 128];  // 32768 B (Hs; becomes HsNew after stage3)
  __shared__ __align__(16) uint16_t ldsHp[BM * 128];  // 32768 B (Hp)
  __shared__ __align__(16) uint16_t ldsB[CHUNK_E];    // 21504 B weight-chunk staging

  const int tid = threadIdx.x;
  const int lane = tid & 63, wid = tid >> 6;
  const int q = lane >> 4, cl = lane & 15;
  const int rowbase = blockIdx.x * BM;
  const int arow = wid * 16 + cl;

  // ---- phase 0: stage X, Hs, Hp into LDS (bf16, XOR-swizzled rows) ----
  #pragma unroll
  for (int pass = 0; pass < 32; ++pass) {           // X: 4 rows/pass, float2
    int row = pass * 4 + (tid >> 7);
    int c2 = (tid & 127) * 2;
    float v0 = 0.f, v1 = 0.f;
    if (c2 < D_IN) { float2 f = *(const float2*)(x + (size_t)(rowbase + row) * D_IN + c2); v0 = f.x; v1 = f.y; }
    ushort2 b; b.x = f2bf(v0); b.y = f2bf(v1);
    int byteoff = row * 512 + ((c2 * 2) ^ ((row & 7) << 4));
    *(ushort2*)((char*)ldsX + byteoff) = b;
  }
  #pragma unroll
  for (int pass = 0; pass < 8; ++pass) {            // Hs: 16 rows/pass, float4
    int row = pass * 16 + (tid >> 5);
    int c4 = (tid & 31) * 4;
    float v0 = 0.f, v1 = 0.f, v2 = 0.f, v3 = 0.f;
    if (c4 < H_DIM) { float4 f = *(const float4*)(hs_g + (size_t)(rowbase + row) * H_DIM + c4); v0 = f.x; v1 = f.y; v2 = f.z; v3 = f.w; }
    ushort4 b; b.x = f2bf(v0); b.y = f2bf(v1); b.z = f2bf(v2); b.w = f2bf(v3);
    int byteoff = row * 256 + ((c4 * 2) ^ ((row & 7) << 4));
    *(ushort4*)((char*)ldsHs + byteoff) = b;
  }
  #pragma unroll
  for (int pass = 0; pass < 8; ++pass) {            // Hp: 16 rows/pass, float4
    int row = pass * 16 + (tid >> 5);
    int c4 = (tid & 31) * 4;
    float v0 = 0.f, v1 = 0.f, v2 = 0.f, v3 = 0.f;
    if (c4 < H_DIM) { float4 f = *(const float4*)(hp_g + (size_t)(rowbase + row) * H_DIM + c4); v0 = f.x; v1 = f.y; v2 = f.z; v3 = f.w; }
    ushort4 b; b.x = f2bf(v0); b.y = f2bf(v1); b.z = f2bf(v2); b.w = f2bf(v3);
    int byteoff = row * 256 + ((c4 * 2) ^ ((row & 7) << 4));
    *(ushort4*)((char*)ldsHp + byteoff) = b;
  }

  f32x4 acc[21];      // single accumulator array reused by every phase (84 regs)
  uint2 ghp[21];      // packed bf16 intermediates
  uint2 xp[21];
  uint2 up[21];

  // ---- stage2: gh = Hs @ Wh^T  (K=128) ----
  gemm21<KS2, 256>(ws, S2_OFF, ldsHs, ldsB, acc, tid, lane, arow, q);
  pack21(acc, ghp);

  // ---- stage1a: gi = X @ Wi^T  (K=256) ----
  gemm21<KS1, 512>(ws, S1A_OFF, ldsX, ldsB, acc, tid, lane, arow, q);

  // ---- stage3: shared-GRU cell elementwise; HsNew overwrites ldsHs in place ----
  #pragma unroll
  for (int t = 0; t < 7; ++t) {
    int c = t * 16 + cl;
    bool valid = c < H_DIM;
    float bir = 0, biz = 0, bin = 0, bhr = 0, bhz = 0, bhn = 0;
    if (valid) {
      bir = bi[c]; biz = bi[H_DIM + c]; bin = bi[2 * H_DIM + c];
      bhr = bh[c]; bhz = bh[H_DIM + c]; bhn = bh[2 * H_DIM + c];
    }
    #pragma unroll
    for (int r = 0; r < 4; ++r) {
      int rl = wid * 16 + q * 4 + r;
      float gir = acc[t][r]      + bir;
      float giz = acc[7 + t][r]  + biz;
      float gin = acc[14 + t][r] + bin;
      float ghr = xpget(ghp[t], r)      + bhr;
      float ghz = xpget(ghp[7 + t], r)  + bhz;
      float ghn = xpget(ghp[14 + t], r) + bhn;
      float rr = sigmoidf_(gir + ghr);
      float zz = sigmoidf_(giz + ghz);
      float nn = tanhf_(gin + rr * ghn);
      int hb = rl * 256 + ((c * 2) ^ ((rl & 7) << 4));
      float hsp = bf2f(*(const uint16_t*)((const char*)ldsHs + hb));
      float hsn = (1.f - zz) * nn + zz * hsp;
      *(uint16_t*)((char*)ldsHs + hb) = f2bf(hsn);   // pad cols compute exactly 0
    }
  }

  // ---- stage1b: task X-proj (W_z, W_r, W_hn), K=256 ----
  gemm21<KS1, 512>(ws, S1B_OFF, ldsX, ldsB, acc, tid, lane, arow, q);
  pack21(acc, xp);

  // ---- stage4a: U-proj from Hp, K=128 ----
  gemm21<KS2, 256>(ws, S4A_OFF, ldsHp, ldsB, acc, tid, lane, arow, q);
  pack21(acc, up);

  // ---- stage4b: Us-proj from HsNew (in ldsHs), K=128 ----
  gemm21<KS2, 256>(ws, S4B_OFF, ldsHs, ldsB, acc, tid, lane, arow, q);

  // ---- stage5: task elementwise + store ----
  #pragma unroll
  for (int t = 0; t < 7; ++t) {
    int c = t * 16 + cl;
    bool valid = c < H_DIM;
    #pragma unroll
    for (int r = 0; r < 4; ++r) {
      int rl = wid * 16 + q * 4 + r;
      float xz = xpget(xp[t], r);
      float xr = xpget(xp[7 + t], r);
      float xh = xpget(xp[14 + t], r);
      float uz = xpget(up[t], r);
      float ur = xpget(up[7 + t], r);
      float uh = xpget(up[14 + t], r);
      float z2 = sigmoidf_(xz + uz + acc[t][r]);
      float r2 = sigmoidf_(xr + ur + acc[7 + t][r]);
      float nm = tanhf_(xh + r2 * uh + acc[14 + t][r]);
      int hb = rl * 256 + ((c * 2) ^ ((rl & 7) << 4));
      float hpv = bf2f(*(const uint16_t*)((const char*)ldsHp + hb));
      float hnew = (1.f - z2) * nm + z2 * hpv;
      if (valid) out[(size_t)(rowbase + rl) * H_DIM + c] = hnew;
    }
  }
}

extern "C" void kernel_launch(void* const* d_in, const int* in_sizes, int n_in,
                              void* d_out, int out_size, void* d_ws, size_t ws_size,
                              hipStream_t stream) {
  const float* x    = (const float*)d_in[0];
  const float* h_p  = (const float*)d_in[1];
  const float* h_s  = (const float*)d_in[2];
  const float* Wi   = (const float*)d_in[3];
  const float* Wh   = (const float*)d_in[4];
  const float* bi   = (const float*)d_in[5];
  const float* bh   = (const float*)d_in[6];
  const float* W_z  = (const float*)d_in[7];
  const float* U_z  = (const float*)d_in[8];
  const float* Us_z = (const float*)d_in[9];
  const float* W_r  = (const float*)d_in[10];
  const float* U_r  = (const float*)d_in[11];
  const float* Us_r = (const float*)d_in[12];
  const float* W_hn = (const float*)d_in[13];
  const float* U_hn = (const float*)d_in[14];
  const float* Us_hn= (const float*)d_in[15];
  uint16_t* ws = (uint16_t*)d_ws;
  float* out = (float*)d_out;

  int rows = in_sizes[0] / D_IN;          // 262144
  prepack_kernel<<<(TOTAL_E + 255) / 256, 256, 0, stream>>>(
      Wi, Wh, W_z, U_z, Us_z, W_r, U_r, Us_r, W_hn, U_hn, Us_hn, ws);
  gru_fused<<<rows / BM, NTHREADS, 0, stream>>>(x, h_p, h_s, bi, bh, ws, out);
}